// Round 5
// baseline (864.885 us; speedup 1.0000x reference)
//
#include <hip/hip_runtime.h>
#include <math.h>
#include <string.h>

#define TILE    32
#define HALO    9
#define IN_T    (TILE + 2*HALO)     /* 50 */
#define IMG_H   512
#define IMG_W   512
#define NPIX    (IMG_H*IMG_W)       /* 262144 = 1<<18 */
#define NIMG    16
#define NSIG    5
#define MAXL    19
#define MIN_SZ  200
#define TSTRIDE 51                  /* padded LDS stride for t-arrays */

struct Taps {
  float k[NSIG][3][MAXL];
  float s2[NSIG];
  int   rad[NSIG];
};

// ---------------------------------------------------------------------------
// Frangi per-sigma. Weights indexed with compile-time constants -> s_load ->
// SGPR. Conv convention (== reference _corr1d):
//   y[i] = sum_j x[i + j - RAD] * k[L-1-j].
//
// Pass 1 (vertical, tap-driven): thread -> (t-col c, 8-row group g).
//   Circular 8-deep x-window in registers; per tap j: 1 LDS read + 24 FMA
//   (8 rows x 3 kernels) with compile-time window slots and SGPR weights.
//   Live state ~ 8 window + 24 acc regs.
// Pass 2 (horizontal): thread -> (row, 4 consecutive cols), circular window
//   with compile-time rotation; then eigenvalues + vesselness.
//
// __launch_bounds__(256,3): cap VGPR ~170. Live set is ~60-80 regs, so no
// spill (round 3 proved cap 64 spills catastrophically; rounds 2/4 proved
// uncapped goes to 204 and collapses occupancy to ~1-2 blocks/CU).
// ---------------------------------------------------------------------------
template<int SIG, int RAD>
__device__ __forceinline__ void do_sigma(const float* __restrict__ sIn,
                                         float* __restrict__ t0,
                                         float* __restrict__ t1,
                                         float* __restrict__ t2,
                                         const Taps& taps, int tid, float* fr)
{
  constexpr int L  = 2*RAD + 1;
  constexpr int WV = TILE + 2*RAD;       // t-array cols (with horizontal halo)

  // ---- pass 1: vertical conv of sIn -> t0(k0), t1(k1), t2(k2) ----
  {
    int c = tid >> 2;                    // t col
    int g = tid & 3;                     // 8-row group
    if (c < WV) {
      int base = (g*8 + HALO - RAD)*IN_T + (c + HALO - RAD);
      float w[8];                        // circular window: x[j..j+7]
#pragma unroll
      for (int m = 0; m < 7; ++m) w[m] = sIn[base + m*IN_T];
      float a0[8] = {0,0,0,0,0,0,0,0};
      float a1[8] = {0,0,0,0,0,0,0,0};
      float a2[8] = {0,0,0,0,0,0,0,0};
#pragma unroll
      for (int j = 0; j < L; ++j) {
        w[(j+7)&7] = sIn[base + (j+7)*IN_T];   // x[j+7] replaces x[j-1]
        float k0 = taps.k[SIG][0][L-1-j];
        float k1 = taps.k[SIG][1][L-1-j];
        float k2 = taps.k[SIG][2][L-1-j];
#pragma unroll
        for (int i = 0; i < 8; ++i) {          // output row g*8+i uses x[i+j]
          float x = w[(j+i)&7];
          a0[i] += x*k0;
          a1[i] += x*k1;
          a2[i] += x*k2;
        }
      }
      int tb = g*8*TSTRIDE + c;
#pragma unroll
      for (int i = 0; i < 8; ++i) {
        t0[tb + i*TSTRIDE] = a0[i];
        t1[tb + i*TSTRIDE] = a1[i];
        t2[tb + i*TSTRIDE] = a2[i];
      }
    }
  }
  __syncthreads();

  // ---- pass 2: horizontal conv + vesselness ----
  {
    int r    = tid >> 3;
    int c0   = (tid & 7) * 4;
    int base = r*TSTRIDE + c0;
    float hrr[4] = {0,0,0,0}, hrc[4] = {0,0,0,0}, hcc[4] = {0,0,0,0};
    float u0[4], u1[4], u2[4];           // circular window, col c0+m at slot m&3
#pragma unroll
    for (int k = 0; k < 4; ++k) { u0[k] = t0[base+k]; u1[k] = t1[base+k]; u2[k] = t2[base+k]; }
#pragma unroll
    for (int j = 0; j < L; ++j) {
      float w0 = taps.k[SIG][0][L-1-j];
      float w1 = taps.k[SIG][1][L-1-j];
      float w2 = taps.k[SIG][2][L-1-j];
#pragma unroll
      for (int k = 0; k < 4; ++k) {
        hrr[k] += u2[(j+k)&3]*w0;        // Hrr = vert k2 (.) horiz k0
        hrc[k] += u1[(j+k)&3]*w1;        // Hrc = vert k1 (.) horiz k1
        hcc[k] += u0[(j+k)&3]*w2;        // Hcc = vert k0 (.) horiz k2
      }
      if (j < L-1) {
        u0[j&3] = t0[base + j + 4];
        u1[j&3] = t1[base + j + 4];
        u2[j&3] = t2[base + j + 4];
      }
    }
    float s2 = taps.s2[SIG];
#pragma unroll
    for (int k = 0; k < 4; ++k) {
      float Hrr = hrr[k]*s2, Hrc = hrc[k]*s2, Hcc = hcc[k]*s2;
      float mid  = 0.5f*(Hrr + Hcc);
      float dif  = 0.5f*(Hrr - Hcc);
      float disc = sqrtf(dif*dif + Hrc*Hrc);
      float ehi  = mid + disc;
      float elo  = mid - disc;
      bool  sm   = fabsf(ehi) <= fabsf(elo);
      float lam1 = sm ? ehi : elo;
      float lam2 = sm ? elo : ehi;
      float lam2c = fmaxf(lam2, 1e-10f);
      float q    = lam1 / lam2c;
      float rb2  = q*q;
      float ssq  = lam1*lam1 + lam2*lam2;
      float v    = expf((-rb2)/2.0f) * (1.0f - expf((-ssq)/50.0f));
      fr[k] = fmaxf(fr[k], v);
    }
  }
  __syncthreads();                       // t-arrays free for next sigma
}

__global__ __launch_bounds__(256, 3)
void frangi_label_kernel(const float* __restrict__ img,
                         int* __restrict__ labels,
                         int* __restrict__ sizes,
                         Taps taps)
{
  __shared__ float sIn[IN_T*IN_T];
  __shared__ float t0[TILE*TSTRIDE];
  __shared__ float t1[TILE*TSTRIDE];
  __shared__ float t2[TILE*TSTRIDE];

  const int tid    = threadIdx.x;
  const int imgIdx = blockIdx.y;
  const int tIdx   = blockIdx.x;
  const int tr0    = (tIdx >> 4) * TILE;
  const int tc0    = (tIdx & 15) * TILE;
  const float* __restrict__ im = img + (size_t)imgIdx * NPIX;

  // load halo tile: reflect ('symmetric') padding, negate+scale: -(x*500)
  for (int i = tid; i < IN_T*IN_T; i += 256) {
    int r = i / IN_T;
    int c = i - r*IN_T;
    int gr = tr0 - HALO + r;
    int gc = tc0 - HALO + c;
    gr = (gr < 0) ? (-1 - gr) : ((gr >= IMG_H) ? (2*IMG_H - 1 - gr) : gr);
    gc = (gc < 0) ? (-1 - gc) : ((gc >= IMG_W) ? (2*IMG_W - 1 - gc) : gc);
    sIn[i] = -(im[gr*IMG_W + gc] * 500.0f);
  }
  __syncthreads();

  float fr[4] = {0.0f, 0.0f, 0.0f, 0.0f};
  do_sigma<0,4>(sIn, t0, t1, t2, taps, tid, fr);   // sigma 1.0
  do_sigma<1,5>(sIn, t0, t1, t2, taps, tid, fr);   // sigma 1.3
  do_sigma<2,6>(sIn, t0, t1, t2, taps, tid, fr);   // sigma 1.6
  do_sigma<3,8>(sIn, t0, t1, t2, taps, tid, fr);   // sigma 1.9
  do_sigma<4,9>(sIn, t0, t1, t2, taps, tid, fr);   // sigma 2.2

  const int r  = tid >> 3;
  const int c0 = (tid & 7) * 4;
  const int gr = tr0 + r;
  const size_t imgBase = (size_t)imgIdx * NPIX;
#pragma unroll
  for (int k = 0; k < 4; ++k) {
    int p = gr*IMG_W + tc0 + c0 + k;
    float x = im[p];
    bool m = (x >= 0.1f) && (x <= 0.5f) && (fr[k] >= 0.2f);
    labels[imgBase + p] = m ? p : -1;
    sizes[imgBase + p]  = 0;
  }
}

// ---------------------------------------------------------------------------
// 8-connected CCL: atomic union-find (min-index root), then size filter.
// ---------------------------------------------------------------------------
__device__ __forceinline__ int ldA(const int* p) {
  return __hip_atomic_load(p, __ATOMIC_RELAXED, __HIP_MEMORY_SCOPE_AGENT);
}
__device__ __forceinline__ int rootOf(const int* L, int x) {
  int pa = ldA(&L[x]);
  while (pa != x) { int g = ldA(&L[pa]); x = pa; pa = g; }
  return x;
}

__global__ __launch_bounds__(256)
void merge_kernel(int* __restrict__ labels)
{
  int gid = blockIdx.x*256 + threadIdx.x;
  int img = gid >> 18;
  int p   = gid & (NPIX - 1);
  int* L  = labels + ((size_t)img << 18);
  if (L[p] < 0) return;
  int r = p >> 9, c = p & (IMG_W - 1);
  const int dr[4] = {0,-1,-1,-1};
  const int dc[4] = {-1,-1,0,1};
#pragma unroll
  for (int k = 0; k < 4; ++k) {
    int nr = r + dr[k], nc = c + dc[k];
    if (nr < 0 || nc < 0 || nc >= IMG_W) continue;
    int q = (nr << 9) | nc;
    if (L[q] < 0) continue;
    int a = p, b = q;
    while (true) {
      a = rootOf(L, a);
      b = rootOf(L, b);
      if (a == b) break;
      int hi = a > b ? a : b;
      int lo = a < b ? a : b;
      int old = atomicCAS(&L[hi], hi, lo);     // link high root under low root
      if (old == hi) break;
      a = old; b = lo;
    }
  }
}

// compress to root + run-length-aggregated size count, fused.
__global__ __launch_bounds__(256)
void compress_count_kernel(int* __restrict__ labels, int* __restrict__ sizes)
{
  int gid = blockIdx.x*256 + threadIdx.x;
  int img = gid >> 18;
  int p   = gid & (NPIX - 1);
  int* L  = labels + ((size_t)img << 18);
  int rt  = -1;
  if (ldA(&L[p]) >= 0) {
    rt = rootOf(L, p);
    __hip_atomic_store(&L[p], rt, __ATOMIC_RELAXED, __HIP_MEMORY_SCOPE_AGENT);
  }
  int lane = threadIdx.x & 63;
  int left = __shfl_up(rt, 1);
  bool head = (lane == 0) || (left != rt);
  unsigned long long hb = __ballot(head);
  if (rt >= 0 && head) {
    unsigned long long rest = (hb >> 1) >> lane;   // heads strictly above
    int len = rest ? __ffsll((long long)rest) : (64 - lane);
    atomicAdd(&sizes[((size_t)img << 18) + rt], len);
  }
}

__global__ __launch_bounds__(256)
void output_kernel(const int* __restrict__ labels, const int* __restrict__ sizes,
                   float* __restrict__ out)
{
  int gid = blockIdx.x*256 + threadIdx.x;
  int l = labels[gid];
  float v = 0.0f;
  if (l >= 0) {
    int img = gid >> 18;
    v = (sizes[((size_t)img << 18) + l] >= MIN_SZ) ? 1.0f : 0.0f;
  }
  out[gid] = v;
}

// ---------------------------------------------------------------------------
// Host: scipy.ndimage-style Gaussian derivative kernels (truncate=4), double
// precision exactly as numpy computes them, cast to f32.
// ---------------------------------------------------------------------------
static void gauss1d(double sigma, int order, int rad, float* out)
{
  int L = 2*rad + 1;
  double phi[MAXL];
  double s = 0.0;
  for (int i = 0; i < L; ++i) {
    double x = (double)(i - rad);
    phi[i] = exp(-0.5*x*x/(sigma*sigma));
    s += phi[i];
  }
  for (int i = 0; i < L; ++i) phi[i] /= s;
  if (order == 0) {
    for (int i = 0; i < L; ++i) out[i] = (float)phi[i];
    return;
  }
  double q[3] = {1.0, 0.0, 0.0};
  for (int it = 0; it < order; ++it) {
    double nq[3] = {0.0, 0.0, 0.0};
    for (int i = 0; i <= order; ++i) {
      double v = 0.0;
      if (i+1 <= order) v += (double)(i+1) * q[i+1];
      if (i-1 >= 0)     v += (-1.0/(sigma*sigma)) * q[i-1];
      nq[i] = v;
    }
    q[0] = nq[0]; q[1] = nq[1]; q[2] = nq[2];
  }
  for (int i = 0; i < L; ++i) {
    double x = (double)(i - rad);
    double poly = q[0];
    double xp = x;
    for (int e = 1; e <= order; ++e) { poly += xp*q[e]; xp *= x; }
    out[i] = (float)(poly*phi[i]);
  }
}

extern "C" void kernel_launch(void* const* d_in, const int* in_sizes, int n_in,
                              void* d_out, int out_size, void* d_ws, size_t ws_size,
                              hipStream_t stream)
{
  (void)in_sizes; (void)n_in; (void)out_size; (void)ws_size;
  const float* img = (const float*)d_in[0];
  float* out = (float*)d_out;
  int* labels = (int*)d_ws;
  int* sizes  = labels + (size_t)NIMG * NPIX;

  Taps taps;
  memset(&taps, 0, sizeof(taps));
  for (int s = 0; s < NSIG; ++s) {
    double sigma = 1.0 + 0.3 * (double)s;      // np.arange(1.0, 2.5, 0.3)
    int rad = (int)(4.0 * sigma + 0.5);        // 4,5,6,8,9
    taps.rad[s] = rad;
    taps.s2[s]  = (float)(sigma * sigma);
    for (int o = 0; o < 3; ++o) gauss1d(sigma, o, rad, taps.k[s][o]);
  }

  dim3 gridF(NPIX / (TILE*TILE), NIMG);        // 256 tiles x 16 images
  frangi_label_kernel<<<gridF, 256, 0, stream>>>(img, labels, sizes, taps);

  int blocks = (NIMG * NPIX) / 256;            // 16384
  merge_kernel         <<<blocks, 256, 0, stream>>>(labels);
  compress_count_kernel<<<blocks, 256, 0, stream>>>(labels, sizes);
  output_kernel        <<<blocks, 256, 0, stream>>>(labels, sizes, out);
}

// Round 6
// 461.515 us; speedup vs baseline: 1.8740x; 1.8740x over previous
//
#include <hip/hip_runtime.h>
#include <math.h>
#include <string.h>

#define TILE    32
#define HALO    9
#define IN_T    (TILE + 2*HALO)     /* 50 */
#define IMG_H   512
#define IMG_W   512
#define NPIX    (IMG_H*IMG_W)       /* 262144 = 1<<18 */
#define NIMG    16
#define NSIG    5
#define MAXL    19
#define MIN_SZ  200
#define TSTRIDE 51                  /* padded LDS stride for t-arrays */

struct Taps {
  float k[NSIG][3][MAXL];
  float s2[NSIG];
  int   rad[NSIG];
};

// ---------------------------------------------------------------------------
// Frangi per-sigma. Weights indexed with compile-time constants -> s_load ->
// SGPR. Conv convention (== reference _corr1d):
//   y[i] = sum_j x[i + j - RAD] * k[L-1-j].
//
// Register-pressure discipline: the tap loops are fully unrolled (needed for
// compile-time circular-window slots + SGPR weights), but a
// sched_barrier(0) at the END OF EACH TAP BODY stops the scheduler from
// hoisting LDS reads across taps. Rounds 2-5 showed: without this the
// scheduler builds a ~200-VGPR live set; launch_bounds caps then spill
// (FETCH 1GB+) instead of de-hoisting. Live set per tap ~40 regs.
// ---------------------------------------------------------------------------
template<int SIG, int RAD>
__device__ __forceinline__ void do_sigma(const float* __restrict__ sIn,
                                         float* __restrict__ t0,
                                         float* __restrict__ t1,
                                         float* __restrict__ t2,
                                         const Taps& taps, int tid, float* fr)
{
  constexpr int L  = 2*RAD + 1;
  constexpr int WV = TILE + 2*RAD;       // t-array cols (with horizontal halo)

  // ---- pass 1: vertical conv of sIn -> t0(k0), t1(k1), t2(k2) ----
  {
    int c = tid >> 2;                    // t col
    int g = tid & 3;                     // 8-row group
    if (c < WV) {
      int base = (g*8 + HALO - RAD)*IN_T + (c + HALO - RAD);
      float w[8];                        // circular window: x[j..j+7]
#pragma unroll
      for (int m = 0; m < 7; ++m) w[m] = sIn[base + m*IN_T];
      float a0[8] = {0,0,0,0,0,0,0,0};
      float a1[8] = {0,0,0,0,0,0,0,0};
      float a2[8] = {0,0,0,0,0,0,0,0};
#pragma unroll
      for (int j = 0; j < L; ++j) {
        w[(j+7)&7] = sIn[base + (j+7)*IN_T];   // x[j+7] replaces x[j-1]
        float k0 = taps.k[SIG][0][L-1-j];
        float k1 = taps.k[SIG][1][L-1-j];
        float k2 = taps.k[SIG][2][L-1-j];
#pragma unroll
        for (int i = 0; i < 8; ++i) {          // output row g*8+i uses x[i+j]
          float x = w[(j+i)&7];
          a0[i] += x*k0;
          a1[i] += x*k1;
          a2[i] += x*k2;
        }
        __builtin_amdgcn_sched_barrier(0);     // no hoisting across taps
      }
      int tb = g*8*TSTRIDE + c;
#pragma unroll
      for (int i = 0; i < 8; ++i) {
        t0[tb + i*TSTRIDE] = a0[i];
        t1[tb + i*TSTRIDE] = a1[i];
        t2[tb + i*TSTRIDE] = a2[i];
      }
    }
  }
  __syncthreads();

  // ---- pass 2: horizontal conv + vesselness ----
  {
    int r    = tid >> 3;
    int c0   = (tid & 7) * 4;
    int base = r*TSTRIDE + c0;
    float hrr[4] = {0,0,0,0}, hrc[4] = {0,0,0,0}, hcc[4] = {0,0,0,0};
    float u0[4], u1[4], u2[4];           // circular window, col c0+m at slot m&3
#pragma unroll
    for (int k = 0; k < 4; ++k) { u0[k] = t0[base+k]; u1[k] = t1[base+k]; u2[k] = t2[base+k]; }
#pragma unroll
    for (int j = 0; j < L; ++j) {
      float w0 = taps.k[SIG][0][L-1-j];
      float w1 = taps.k[SIG][1][L-1-j];
      float w2 = taps.k[SIG][2][L-1-j];
#pragma unroll
      for (int k = 0; k < 4; ++k) {
        hrr[k] += u2[(j+k)&3]*w0;        // Hrr = vert k2 (.) horiz k0
        hrc[k] += u1[(j+k)&3]*w1;        // Hrc = vert k1 (.) horiz k1
        hcc[k] += u0[(j+k)&3]*w2;        // Hcc = vert k0 (.) horiz k2
      }
      if (j < L-1) {
        u0[j&3] = t0[base + j + 4];
        u1[j&3] = t1[base + j + 4];
        u2[j&3] = t2[base + j + 4];
      }
      __builtin_amdgcn_sched_barrier(0);       // no hoisting across taps
    }
    float s2 = taps.s2[SIG];
#pragma unroll
    for (int k = 0; k < 4; ++k) {
      float Hrr = hrr[k]*s2, Hrc = hrc[k]*s2, Hcc = hcc[k]*s2;
      float mid  = 0.5f*(Hrr + Hcc);
      float dif  = 0.5f*(Hrr - Hcc);
      float disc = sqrtf(dif*dif + Hrc*Hrc);
      float ehi  = mid + disc;
      float elo  = mid - disc;
      bool  sm   = fabsf(ehi) <= fabsf(elo);
      float lam1 = sm ? ehi : elo;
      float lam2 = sm ? elo : ehi;
      float lam2c = fmaxf(lam2, 1e-10f);
      float q    = lam1 / lam2c;
      float rb2  = q*q;
      float ssq  = lam1*lam1 + lam2*lam2;
      float v    = expf((-rb2)/2.0f) * (1.0f - expf((-ssq)/50.0f));
      fr[k] = fmaxf(fr[k], v);
    }
  }
  __syncthreads();                       // t-arrays free for next sigma
}

__global__ __launch_bounds__(256)
void frangi_label_kernel(const float* __restrict__ img,
                         int* __restrict__ labels,
                         int* __restrict__ sizes,
                         Taps taps)
{
  __shared__ float sIn[IN_T*IN_T];
  __shared__ float t0[TILE*TSTRIDE];
  __shared__ float t1[TILE*TSTRIDE];
  __shared__ float t2[TILE*TSTRIDE];

  const int tid    = threadIdx.x;
  const int imgIdx = blockIdx.y;
  const int tIdx   = blockIdx.x;
  const int tr0    = (tIdx >> 4) * TILE;
  const int tc0    = (tIdx & 15) * TILE;
  const float* __restrict__ im = img + (size_t)imgIdx * NPIX;

  // load halo tile: reflect ('symmetric') padding, negate+scale: -(x*500)
  for (int i = tid; i < IN_T*IN_T; i += 256) {
    int r = i / IN_T;
    int c = i - r*IN_T;
    int gr = tr0 - HALO + r;
    int gc = tc0 - HALO + c;
    gr = (gr < 0) ? (-1 - gr) : ((gr >= IMG_H) ? (2*IMG_H - 1 - gr) : gr);
    gc = (gc < 0) ? (-1 - gc) : ((gc >= IMG_W) ? (2*IMG_W - 1 - gc) : gc);
    sIn[i] = -(im[gr*IMG_W + gc] * 500.0f);
  }
  __syncthreads();

  float fr[4] = {0.0f, 0.0f, 0.0f, 0.0f};
  do_sigma<0,4>(sIn, t0, t1, t2, taps, tid, fr);   // sigma 1.0
  do_sigma<1,5>(sIn, t0, t1, t2, taps, tid, fr);   // sigma 1.3
  do_sigma<2,6>(sIn, t0, t1, t2, taps, tid, fr);   // sigma 1.6
  do_sigma<3,8>(sIn, t0, t1, t2, taps, tid, fr);   // sigma 1.9
  do_sigma<4,9>(sIn, t0, t1, t2, taps, tid, fr);   // sigma 2.2

  const int r  = tid >> 3;
  const int c0 = (tid & 7) * 4;
  const int gr = tr0 + r;
  const size_t imgBase = (size_t)imgIdx * NPIX;
#pragma unroll
  for (int k = 0; k < 4; ++k) {
    int p = gr*IMG_W + tc0 + c0 + k;
    float x = im[p];
    bool m = (x >= 0.1f) && (x <= 0.5f) && (fr[k] >= 0.2f);
    labels[imgBase + p] = m ? p : -1;
    sizes[imgBase + p]  = 0;
  }
}

// ---------------------------------------------------------------------------
// 8-connected CCL: atomic union-find (min-index root), then size filter.
// ---------------------------------------------------------------------------
__device__ __forceinline__ int ldA(const int* p) {
  return __hip_atomic_load(p, __ATOMIC_RELAXED, __HIP_MEMORY_SCOPE_AGENT);
}
__device__ __forceinline__ int rootOf(const int* L, int x) {
  int pa = ldA(&L[x]);
  while (pa != x) { int g = ldA(&L[pa]); x = pa; pa = g; }
  return x;
}

__global__ __launch_bounds__(256)
void merge_kernel(int* __restrict__ labels)
{
  int gid = blockIdx.x*256 + threadIdx.x;
  int img = gid >> 18;
  int p   = gid & (NPIX - 1);
  int* L  = labels + ((size_t)img << 18);
  if (L[p] < 0) return;
  int r = p >> 9, c = p & (IMG_W - 1);
  const int dr[4] = {0,-1,-1,-1};
  const int dc[4] = {-1,-1,0,1};
#pragma unroll
  for (int k = 0; k < 4; ++k) {
    int nr = r + dr[k], nc = c + dc[k];
    if (nr < 0 || nc < 0 || nc >= IMG_W) continue;
    int q = (nr << 9) | nc;
    if (L[q] < 0) continue;
    int a = p, b = q;
    while (true) {
      a = rootOf(L, a);
      b = rootOf(L, b);
      if (a == b) break;
      int hi = a > b ? a : b;
      int lo = a < b ? a : b;
      int old = atomicCAS(&L[hi], hi, lo);     // link high root under low root
      if (old == hi) break;
      a = old; b = lo;
    }
  }
}

// compress to root + run-length-aggregated size count, fused.
__global__ __launch_bounds__(256)
void compress_count_kernel(int* __restrict__ labels, int* __restrict__ sizes)
{
  int gid = blockIdx.x*256 + threadIdx.x;
  int img = gid >> 18;
  int p   = gid & (NPIX - 1);
  int* L  = labels + ((size_t)img << 18);
  int rt  = -1;
  if (ldA(&L[p]) >= 0) {
    rt = rootOf(L, p);
    __hip_atomic_store(&L[p], rt, __ATOMIC_RELAXED, __HIP_MEMORY_SCOPE_AGENT);
  }
  int lane = threadIdx.x & 63;
  int left = __shfl_up(rt, 1);
  bool head = (lane == 0) || (left != rt);
  unsigned long long hb = __ballot(head);
  if (rt >= 0 && head) {
    unsigned long long rest = (hb >> 1) >> lane;   // heads strictly above
    int len = rest ? __ffsll((long long)rest) : (64 - lane);
    atomicAdd(&sizes[((size_t)img << 18) + rt], len);
  }
}

__global__ __launch_bounds__(256)
void output_kernel(const int* __restrict__ labels, const int* __restrict__ sizes,
                   float* __restrict__ out)
{
  int gid = blockIdx.x*256 + threadIdx.x;
  int l = labels[gid];
  float v = 0.0f;
  if (l >= 0) {
    int img = gid >> 18;
    v = (sizes[((size_t)img << 18) + l] >= MIN_SZ) ? 1.0f : 0.0f;
  }
  out[gid] = v;
}

// ---------------------------------------------------------------------------
// Host: scipy.ndimage-style Gaussian derivative kernels (truncate=4), double
// precision exactly as numpy computes them, cast to f32.
// ---------------------------------------------------------------------------
static void gauss1d(double sigma, int order, int rad, float* out)
{
  int L = 2*rad + 1;
  double phi[MAXL];
  double s = 0.0;
  for (int i = 0; i < L; ++i) {
    double x = (double)(i - rad);
    phi[i] = exp(-0.5*x*x/(sigma*sigma));
    s += phi[i];
  }
  for (int i = 0; i < L; ++i) phi[i] /= s;
  if (order == 0) {
    for (int i = 0; i < L; ++i) out[i] = (float)phi[i];
    return;
  }
  double q[3] = {1.0, 0.0, 0.0};
  for (int it = 0; it < order; ++it) {
    double nq[3] = {0.0, 0.0, 0.0};
    for (int i = 0; i <= order; ++i) {
      double v = 0.0;
      if (i+1 <= order) v += (double)(i+1) * q[i+1];
      if (i-1 >= 0)     v += (-1.0/(sigma*sigma)) * q[i-1];
      nq[i] = v;
    }
    q[0] = nq[0]; q[1] = nq[1]; q[2] = nq[2];
  }
  for (int i = 0; i < L; ++i) {
    double x = (double)(i - rad);
    double poly = q[0];
    double xp = x;
    for (int e = 1; e <= order; ++e) { poly += xp*q[e]; xp *= x; }
    out[i] = (float)(poly*phi[i]);
  }
}

extern "C" void kernel_launch(void* const* d_in, const int* in_sizes, int n_in,
                              void* d_out, int out_size, void* d_ws, size_t ws_size,
                              hipStream_t stream)
{
  (void)in_sizes; (void)n_in; (void)out_size; (void)ws_size;
  const float* img = (const float*)d_in[0];
  float* out = (float*)d_out;
  int* labels = (int*)d_ws;
  int* sizes  = labels + (size_t)NIMG * NPIX;

  Taps taps;
  memset(&taps, 0, sizeof(taps));
  for (int s = 0; s < NSIG; ++s) {
    double sigma = 1.0 + 0.3 * (double)s;      // np.arange(1.0, 2.5, 0.3)
    int rad = (int)(4.0 * sigma + 0.5);        // 4,5,6,8,9
    taps.rad[s] = rad;
    taps.s2[s]  = (float)(sigma * sigma);
    for (int o = 0; o < 3; ++o) gauss1d(sigma, o, rad, taps.k[s][o]);
  }

  dim3 gridF(NPIX / (TILE*TILE), NIMG);        // 256 tiles x 16 images
  frangi_label_kernel<<<gridF, 256, 0, stream>>>(img, labels, sizes, taps);

  int blocks = (NIMG * NPIX) / 256;            // 16384
  merge_kernel         <<<blocks, 256, 0, stream>>>(labels);
  compress_count_kernel<<<blocks, 256, 0, stream>>>(labels, sizes);
  output_kernel        <<<blocks, 256, 0, stream>>>(labels, sizes, out);
}

// Round 7
// 294.355 us; speedup vs baseline: 2.9382x; 1.5679x over previous
//
#include <hip/hip_runtime.h>
#include <math.h>
#include <string.h>

#define IMG_H   512
#define IMG_W   512
#define NPIX    (IMG_H*IMG_W)       /* 262144 = 1<<18 */
#define NIMG    16
#define NSIG    5
#define MIN_SZ  200
#define SSTR    60                  /* sIn stride (dwords): mult of 4, !=0 mod 32 */
#define SROWS   50
#define TSTR    60                  /* t stride (dwords) */
#define KVL     20
#define KHL     24

typedef float f4 __attribute__((ext_vector_type(4)));

// Host-precomputed tap tables (kernarg -> s_load, off the VALU path):
//  kv[s][o][j]  = k_o[L-1-j]                      (vertical taps, pre-reversed)
//  kh[s][o][j'] = (d<=j'<d+L) ? k_o[L-1-(j'-d)]:0 (horizontal: reversed, shifted
//                  by per-sigma alignment delta d, zero-padded to L4)
struct KTab {
  float kv[NSIG][3][KVL];
  float kh[NSIG][3][KHL];
  float s2[NSIG];
};

// ---------------------------------------------------------------------------
// Coordinates: sIn column index cs = tile col + 12 (fixed for all sigmas).
// Image region loaded into cs in [3,53); cs in [0,3) u [53,60) zero-filled.
// Per sigma (compile-time): CS0 = (12-RAD) & ~3 (aligned window start for
// tile col 0), MLO = CS0/4, G = 8 + L4/4 column-groups, L4 = padded tap count.
// Zero-padded kh taps only ever multiply fully-defined t values (exact 0).
//
// Pass 1 (vertical): thread -> slots (r = tid&31, group g) ; per tap j:
//   2x ds_read_b128 (4-col slice) + 24 FMA. Runtime j loop (unroll 1) keeps
//   the scheduler window small -> bounded VGPR (round-1-proven pattern).
// Pass 2 (horizontal): thread -> (row, 4 cols); sliding 2xf4 window, inner
//   4-tap x 4-out block fully unrolled (compile-time selects), outer runtime.
// ---------------------------------------------------------------------------
template<int SIG, int RAD, int MLO, int G, int CS0, int L4>
__device__ __forceinline__ void do_sigma(const float* __restrict__ sIn,
                                         float* __restrict__ t0,
                                         float* __restrict__ t1,
                                         float* __restrict__ t2,
                                         const KTab& kt, int tid, float* fr)
{
  constexpr int L = 2*RAD + 1;

  // ---- pass 1: vertical conv -> t0(k0), t1(k1), t2(k2), f4 per slot ----
  {
    int r0 = tid & 31;
    int g0 = tid >> 5;                 // slot A group in [0,8): always < G
    int g1 = g0 + 8;                   // slot B group in [8,16)
    bool vB = (g1 < G);
    int aA = (r0 + 9 - RAD)*SSTR + 4*(MLO + g0);
    int aB = vB ? ((r0 + 9 - RAD)*SSTR + 4*(MLO + g1)) : aA;
    f4 A0 = {0,0,0,0}, A1 = {0,0,0,0}, A2 = {0,0,0,0};
    f4 B0 = {0,0,0,0}, B1 = {0,0,0,0}, B2 = {0,0,0,0};
#pragma unroll 1
    for (int j = 0; j < L; ++j) {
      float w0 = kt.kv[SIG][0][j];
      float w1 = kt.kv[SIG][1][j];
      float w2 = kt.kv[SIG][2][j];
      f4 xA = *(const f4*)(sIn + aA); aA += SSTR;
      f4 xB = *(const f4*)(sIn + aB); aB += SSTR;
      A0 += xA*w0; A1 += xA*w1; A2 += xA*w2;
      B0 += xB*w0; B1 += xB*w1; B2 += xB*w2;
    }
    int tA = r0*TSTR + 4*(MLO + g0);
    *(f4*)(t0 + tA) = A0; *(f4*)(t1 + tA) = A1; *(f4*)(t2 + tA) = A2;
    if (vB) {
      int tB = r0*TSTR + 4*(MLO + g1);
      *(f4*)(t0 + tB) = B0; *(f4*)(t1 + tB) = B1; *(f4*)(t2 + tB) = B2;
    }
  }
  __syncthreads();

  // ---- pass 2: horizontal conv + vesselness ----
  {
    int r  = tid >> 3;
    int c0 = (tid & 7) * 4;
    int wa = r*TSTR + CS0 + c0;
    f4 A0 = *(const f4*)(t0 + wa);
    f4 A1 = *(const f4*)(t1 + wa);
    f4 A2 = *(const f4*)(t2 + wa);
    f4 hrr = {0,0,0,0}, hrc = {0,0,0,0}, hcc = {0,0,0,0};
#pragma unroll 1
    for (int a = 0; a < L4/4; ++a) {
      f4 w0 = *(const f4*)&kt.kh[SIG][0][4*a];   // k0 -> Hrr (applied to t2)
      f4 w1 = *(const f4*)&kt.kh[SIG][1][4*a];   // k1 -> Hrc (t1)
      f4 w2 = *(const f4*)&kt.kh[SIG][2][4*a];   // k2 -> Hcc (t0)
      wa += 4;
      f4 B0 = *(const f4*)(t0 + wa);
      f4 B1 = *(const f4*)(t1 + wa);
      f4 B2 = *(const f4*)(t2 + wa);
#pragma unroll
      for (int b = 0; b < 4; ++b) {
#pragma unroll
        for (int k = 0; k < 4; ++k) {
          constexpr int dummy = 0; (void)dummy;
          int e = b + k;                         // compile-time under unroll
          float x2 = (e < 4) ? A2[e] : B2[e-4];
          float x1 = (e < 4) ? A1[e] : B1[e-4];
          float x0 = (e < 4) ? A0[e] : B0[e-4];
          hrr[k] += x2 * w0[b];
          hrc[k] += x1 * w1[b];
          hcc[k] += x0 * w2[b];
        }
      }
      A0 = B0; A1 = B1; A2 = B2;
    }
    float s2v = kt.s2[SIG];
#pragma unroll
    for (int k = 0; k < 4; ++k) {
      float Hrr = hrr[k]*s2v, Hrc = hrc[k]*s2v, Hcc = hcc[k]*s2v;
      float mid  = 0.5f*(Hrr + Hcc);
      float dif  = 0.5f*(Hrr - Hcc);
      float disc = sqrtf(dif*dif + Hrc*Hrc);
      float ehi  = mid + disc;
      float elo  = mid - disc;
      bool  sm   = fabsf(ehi) <= fabsf(elo);
      float lam1 = sm ? ehi : elo;
      float lam2 = sm ? elo : ehi;
      float lam2c = fmaxf(lam2, 1e-10f);
      float q    = lam1 / lam2c;
      float rb2  = q*q;
      float ssq  = lam1*lam1 + lam2*lam2;
      float v    = expf((-rb2)/2.0f) * (1.0f - expf((-ssq)/50.0f));
      fr[k] = fmaxf(fr[k], v);
    }
  }
  __syncthreads();                     // t arrays free for next sigma
}

__global__ __launch_bounds__(256)
void frangi_label_kernel(const float* __restrict__ img,
                         int* __restrict__ labels,
                         int* __restrict__ sizes,
                         KTab kt)
{
  __shared__ float sIn[SROWS*SSTR];    // 12000 B
  __shared__ float t0[32*TSTR];        // 7680 B x3
  __shared__ float t1[32*TSTR];
  __shared__ float t2[32*TSTR];

  const int tid    = threadIdx.x;
  const int imgIdx = blockIdx.y;
  const int tIdx   = blockIdx.x;
  const int tr0    = (tIdx >> 4) * 32;
  const int tc0    = (tIdx & 15) * 32;
  const float* __restrict__ im = img + (size_t)imgIdx * NPIX;

  // fill sIn: zeros outside, reflect('symmetric') + negate/scale inside.
  // row r -> tile row r-9 ; col cs -> tile col cs-12 (loaded for cs in [3,53))
  for (int idx = tid; idx < SROWS*64; idx += 256) {
    int r  = idx >> 6;
    int cs = idx & 63;
    if (cs < SSTR) {
      float v = 0.0f;
      if (cs >= 3 && cs < 53) {
        int gr = tr0 + r - 9;
        int gc = tc0 + cs - 12;
        gr = (gr < 0) ? (-1 - gr) : ((gr >= IMG_H) ? (2*IMG_H - 1 - gr) : gr);
        gc = (gc < 0) ? (-1 - gc) : ((gc >= IMG_W) ? (2*IMG_W - 1 - gc) : gc);
        v = -(im[gr*IMG_W + gc] * 500.0f);
      }
      sIn[r*SSTR + cs] = v;
    }
  }
  __syncthreads();

  float fr[4] = {0.0f, 0.0f, 0.0f, 0.0f};
  //        SIG RAD MLO  G  CS0 L4
  do_sigma<0,  4,  2, 11,  8, 12>(sIn, t0, t1, t2, kt, tid, fr);  // sigma 1.0
  do_sigma<1,  5,  1, 12,  4, 16>(sIn, t0, t1, t2, kt, tid, fr);  // sigma 1.3
  do_sigma<2,  6,  1, 12,  4, 16>(sIn, t0, t1, t2, kt, tid, fr);  // sigma 1.6
  do_sigma<3,  8,  1, 13,  4, 20>(sIn, t0, t1, t2, kt, tid, fr);  // sigma 1.9
  do_sigma<4,  9,  0, 14,  0, 24>(sIn, t0, t1, t2, kt, tid, fr);  // sigma 2.2

  const int r  = tid >> 3;
  const int c0 = (tid & 7) * 4;
  const int gr = tr0 + r;
  const size_t imgBase = (size_t)imgIdx * NPIX;
#pragma unroll
  for (int k = 0; k < 4; ++k) {
    int p = gr*IMG_W + tc0 + c0 + k;
    float x = im[p];
    bool m = (x >= 0.1f) && (x <= 0.5f) && (fr[k] >= 0.2f);
    labels[imgBase + p] = m ? p : -1;
    sizes[imgBase + p]  = 0;
  }
}

// ---------------------------------------------------------------------------
// 8-connected CCL: atomic union-find (min-index root), then size filter.
// ---------------------------------------------------------------------------
__device__ __forceinline__ int ldA(const int* p) {
  return __hip_atomic_load(p, __ATOMIC_RELAXED, __HIP_MEMORY_SCOPE_AGENT);
}
__device__ __forceinline__ int rootOf(const int* L, int x) {
  int pa = ldA(&L[x]);
  while (pa != x) { int g = ldA(&L[pa]); x = pa; pa = g; }
  return x;
}

__global__ __launch_bounds__(256)
void merge_kernel(int* __restrict__ labels)
{
  int gid = blockIdx.x*256 + threadIdx.x;
  int img = gid >> 18;
  int p   = gid & (NPIX - 1);
  int* L  = labels + ((size_t)img << 18);
  if (L[p] < 0) return;
  int r = p >> 9, c = p & (IMG_W - 1);
  const int dr[4] = {0,-1,-1,-1};
  const int dc[4] = {-1,-1,0,1};
#pragma unroll
  for (int k = 0; k < 4; ++k) {
    int nr = r + dr[k], nc = c + dc[k];
    if (nr < 0 || nc < 0 || nc >= IMG_W) continue;
    int q = (nr << 9) | nc;
    if (L[q] < 0) continue;
    int a = p, b = q;
    while (true) {
      a = rootOf(L, a);
      b = rootOf(L, b);
      if (a == b) break;
      int hi = a > b ? a : b;
      int lo = a < b ? a : b;
      int old = atomicCAS(&L[hi], hi, lo);     // link high root under low root
      if (old == hi) break;
      a = old; b = lo;
    }
  }
}

// compress to root + run-length-aggregated size count, fused.
__global__ __launch_bounds__(256)
void compress_count_kernel(int* __restrict__ labels, int* __restrict__ sizes)
{
  int gid = blockIdx.x*256 + threadIdx.x;
  int img = gid >> 18;
  int p   = gid & (NPIX - 1);
  int* L  = labels + ((size_t)img << 18);
  int rt  = -1;
  if (ldA(&L[p]) >= 0) {
    rt = rootOf(L, p);
    __hip_atomic_store(&L[p], rt, __ATOMIC_RELAXED, __HIP_MEMORY_SCOPE_AGENT);
  }
  int lane = threadIdx.x & 63;
  int left = __shfl_up(rt, 1);
  bool head = (lane == 0) || (left != rt);
  unsigned long long hb = __ballot(head);
  if (rt >= 0 && head) {
    unsigned long long rest = (hb >> 1) >> lane;   // heads strictly above
    int len = rest ? __ffsll((long long)rest) : (64 - lane);
    atomicAdd(&sizes[((size_t)img << 18) + rt], len);
  }
}

__global__ __launch_bounds__(256)
void output_kernel(const int* __restrict__ labels, const int* __restrict__ sizes,
                   float* __restrict__ out)
{
  int gid = blockIdx.x*256 + threadIdx.x;
  int l = labels[gid];
  float v = 0.0f;
  if (l >= 0) {
    int img = gid >> 18;
    v = (sizes[((size_t)img << 18) + l] >= MIN_SZ) ? 1.0f : 0.0f;
  }
  out[gid] = v;
}

// ---------------------------------------------------------------------------
// Host: scipy.ndimage-style Gaussian derivative kernels (truncate=4), double
// precision exactly as numpy computes them, cast to f32.
// ---------------------------------------------------------------------------
static void gauss1d(double sigma, int order, int rad, float* out)
{
  int L = 2*rad + 1;
  double phi[24];
  double s = 0.0;
  for (int i = 0; i < L; ++i) {
    double x = (double)(i - rad);
    phi[i] = exp(-0.5*x*x/(sigma*sigma));
    s += phi[i];
  }
  for (int i = 0; i < L; ++i) phi[i] /= s;
  if (order == 0) {
    for (int i = 0; i < L; ++i) out[i] = (float)phi[i];
    return;
  }
  double q[3] = {1.0, 0.0, 0.0};
  for (int it = 0; it < order; ++it) {
    double nq[3] = {0.0, 0.0, 0.0};
    for (int i = 0; i <= order; ++i) {
      double v = 0.0;
      if (i+1 <= order) v += (double)(i+1) * q[i+1];
      if (i-1 >= 0)     v += (-1.0/(sigma*sigma)) * q[i-1];
      nq[i] = v;
    }
    q[0] = nq[0]; q[1] = nq[1]; q[2] = nq[2];
  }
  for (int i = 0; i < L; ++i) {
    double x = (double)(i - rad);
    double poly = q[0];
    double xp = x;
    for (int e = 1; e <= order; ++e) { poly += xp*q[e]; xp *= x; }
    out[i] = (float)(poly*phi[i]);
  }
}

extern "C" void kernel_launch(void* const* d_in, const int* in_sizes, int n_in,
                              void* d_out, int out_size, void* d_ws, size_t ws_size,
                              hipStream_t stream)
{
  (void)in_sizes; (void)n_in; (void)out_size; (void)ws_size;
  const float* img = (const float*)d_in[0];
  float* out = (float*)d_out;
  int* labels = (int*)d_ws;
  int* sizes  = labels + (size_t)NIMG * NPIX;

  KTab kt;
  memset(&kt, 0, sizeof(kt));
  for (int s = 0; s < NSIG; ++s) {
    double sigma = 1.0 + 0.3 * (double)s;      // np.arange(1.0, 2.5, 0.3)
    int rad = (int)(4.0 * sigma + 0.5);        // 4,5,6,8,9
    int L   = 2*rad + 1;
    int dlt = (12 - rad) & 3;                  // horizontal alignment shift
    kt.s2[s] = (float)(sigma * sigma);
    float k[3][24];
    for (int o = 0; o < 3; ++o) gauss1d(sigma, o, rad, k[o]);
    for (int o = 0; o < 3; ++o) {
      for (int j = 0; j < L; ++j)
        kt.kv[s][o][j] = k[o][L-1-j];          // pre-reversed (conv order)
      for (int jp = 0; jp < KHL; ++jp)
        kt.kh[s][o][jp] = (jp >= dlt && jp - dlt < L) ? k[o][L-1-(jp-dlt)] : 0.0f;
    }
  }

  dim3 gridF(NPIX / (32*32), NIMG);            // 256 tiles x 16 images
  frangi_label_kernel<<<gridF, 256, 0, stream>>>(img, labels, sizes, kt);

  int blocks = (NIMG * NPIX) / 256;            // 16384
  merge_kernel         <<<blocks, 256, 0, stream>>>(labels);
  compress_count_kernel<<<blocks, 256, 0, stream>>>(labels, sizes);
  output_kernel        <<<blocks, 256, 0, stream>>>(labels, sizes, out);
}

// Round 8
// 282.640 us; speedup vs baseline: 3.0600x; 1.0414x over previous
//
#include <hip/hip_runtime.h>
#include <math.h>
#include <string.h>

#define IMG_H   512
#define IMG_W   512
#define NPIX    (IMG_H*IMG_W)       /* 262144 = 1<<18 */
#define NIMG    16
#define NSIG    5
#define MIN_SZ  200
#define SSTR    60                  /* sIn stride (dwords) */
#define SROWS   50
#define TSTR    68                  /* t stride (dwords): room for tail prefetch */
#define KVL     20
#define KHL     24

typedef float f4 __attribute__((ext_vector_type(4)));

// Host-precomputed tap tables (kernarg -> s_load, off the VALU path):
//  kv[s][o][j]  = k_o[L-1-j]                      (vertical taps, pre-reversed)
//  kh[s][o][j'] = (d<=j'<d+L) ? k_o[L-1-(j'-d)]:0 (horizontal: reversed, shifted
//                  by per-sigma alignment delta d, zero-padded to L4P)
struct KTab {
  float kv[NSIG][3][KVL];
  float kh[NSIG][3][KHL];
  float s2[NSIG];
};

// ---------------------------------------------------------------------------
// Coordinates: sIn column cs = tile col + 12. Real data in cs [3,53), zeros
// outside. Per sigma: MLO = aligned start group ((12-RAD)>>2), GH = pair-slot
// count = ceil(G/2), L4P = horizontal tap count padded to mult of 8.
//
// Pass 1 (vertical): threads tid < 32*GH each own (row r0, 8-col pair slot).
//   Full waves beyond the slot count skip pass 1 (no masked-FMA waste).
// Pass 2 (horizontal): P/Q ping-pong window, chunk loop 2x-unrolled so all
//   register roles are compile-time (no window-copy movs). Tail prefetch
//   loads a dead value (never multiplied) - TSTR=68 keeps it in-row.
// Consumed-with-nonzero-weight groups are a subset of written groups for
// every sigma (verified per-sigma), so no uninitialized value reaches math.
// ---------------------------------------------------------------------------
template<int SIG, int RAD, int MLO, int GH, int L4P>
__device__ __forceinline__ void do_sigma(const float* __restrict__ sIn,
                                         float* __restrict__ t0,
                                         float* __restrict__ t1,
                                         float* __restrict__ t2,
                                         const KTab& kt, int tid, float* fr)
{
  constexpr int L = 2*RAD + 1;

  // ---- pass 1: vertical conv -> t0(k0), t1(k1), t2(k2) ----
  if (tid < 32*GH) {
    int r0 = tid & 31;
    int h  = tid >> 5;                 // 8-col pair slot
    int a  = (r0 + 9 - RAD)*SSTR + 4*(MLO + 2*h);
    f4 A0={0,0,0,0}, A1={0,0,0,0}, A2={0,0,0,0};
    f4 B0={0,0,0,0}, B1={0,0,0,0}, B2={0,0,0,0};
#pragma unroll 1
    for (int j = 0; j < L; ++j) {
      float w0 = kt.kv[SIG][0][j];
      float w1 = kt.kv[SIG][1][j];
      float w2 = kt.kv[SIG][2][j];
      f4 xA = *(const f4*)(sIn + a);
      f4 xB = *(const f4*)(sIn + a + 4);
      a += SSTR;
      A0 += xA*w0; A1 += xA*w1; A2 += xA*w2;
      B0 += xB*w0; B1 += xB*w1; B2 += xB*w2;
    }
    int tb = r0*TSTR + 4*(MLO + 2*h);
    *(f4*)(t0 + tb)     = A0; *(f4*)(t1 + tb)     = A1; *(f4*)(t2 + tb)     = A2;
    *(f4*)(t0 + tb + 4) = B0; *(f4*)(t1 + tb + 4) = B1; *(f4*)(t2 + tb + 4) = B2;
  }
  __syncthreads();

  // ---- pass 2: horizontal conv + vesselness ----
  {
    int r  = tid >> 3;
    int c0 = (tid & 7) * 4;
    int wa = r*TSTR + 4*MLO + c0;
    f4 P0 = *(const f4*)(t0 + wa);
    f4 P1 = *(const f4*)(t1 + wa);
    f4 P2 = *(const f4*)(t2 + wa);
    f4 Q0 = *(const f4*)(t0 + wa + 4);
    f4 Q1 = *(const f4*)(t1 + wa + 4);
    f4 Q2 = *(const f4*)(t2 + wa + 4);
    wa += 8;
    f4 hrr={0,0,0,0}, hrc={0,0,0,0}, hcc={0,0,0,0};
#pragma unroll 1
    for (int aa = 0; aa < L4P/8; ++aa) {
      {  // chunk 2aa: low=P, high=Q ; then P <- next group
        f4 w0 = *(const f4*)&kt.kh[SIG][0][8*aa];
        f4 w1 = *(const f4*)&kt.kh[SIG][1][8*aa];
        f4 w2 = *(const f4*)&kt.kh[SIG][2][8*aa];
#pragma unroll
        for (int b = 0; b < 4; ++b)
#pragma unroll
          for (int k = 0; k < 4; ++k) {
            int e = b + k;                       // compile-time under unroll
            float x2 = (e < 4) ? P2[e] : Q2[e-4];
            float x1 = (e < 4) ? P1[e] : Q1[e-4];
            float x0 = (e < 4) ? P0[e] : Q0[e-4];
            hrr[k] += x2 * w0[b];                // Hrr = vert k2 (.) horiz k0
            hrc[k] += x1 * w1[b];                // Hrc = vert k1 (.) horiz k1
            hcc[k] += x0 * w2[b];                // Hcc = vert k0 (.) horiz k2
          }
        P0 = *(const f4*)(t0 + wa);
        P1 = *(const f4*)(t1 + wa);
        P2 = *(const f4*)(t2 + wa);
      }
      {  // chunk 2aa+1: low=Q, high=P(new) ; then Q <- next group
        f4 w0 = *(const f4*)&kt.kh[SIG][0][8*aa+4];
        f4 w1 = *(const f4*)&kt.kh[SIG][1][8*aa+4];
        f4 w2 = *(const f4*)&kt.kh[SIG][2][8*aa+4];
#pragma unroll
        for (int b = 0; b < 4; ++b)
#pragma unroll
          for (int k = 0; k < 4; ++k) {
            int e = b + k;
            float x2 = (e < 4) ? Q2[e] : P2[e-4];
            float x1 = (e < 4) ? Q1[e] : P1[e-4];
            float x0 = (e < 4) ? Q0[e] : P0[e-4];
            hrr[k] += x2 * w0[b];
            hrc[k] += x1 * w1[b];
            hcc[k] += x0 * w2[b];
          }
        Q0 = *(const f4*)(t0 + wa + 4);
        Q1 = *(const f4*)(t1 + wa + 4);
        Q2 = *(const f4*)(t2 + wa + 4);
      }
      wa += 8;
    }
    float s2v = kt.s2[SIG];
#pragma unroll
    for (int k = 0; k < 4; ++k) {
      float Hrr = hrr[k]*s2v, Hrc = hrc[k]*s2v, Hcc = hcc[k]*s2v;
      float mid  = 0.5f*(Hrr + Hcc);
      float dif  = 0.5f*(Hrr - Hcc);
      float disc = sqrtf(dif*dif + Hrc*Hrc);
      float ehi  = mid + disc;
      float elo  = mid - disc;
      bool  sm   = fabsf(ehi) <= fabsf(elo);
      float lam1 = sm ? ehi : elo;
      float lam2 = sm ? elo : ehi;
      float lam2c = fmaxf(lam2, 1e-10f);
      float q    = lam1 / lam2c;
      float rb2  = q*q;
      float ssq  = lam1*lam1 + lam2*lam2;
      float v    = expf((-rb2)/2.0f) * (1.0f - expf((-ssq)/50.0f));
      fr[k] = fmaxf(fr[k], v);
    }
  }
  __syncthreads();                     // t arrays free for next sigma
}

__global__ __launch_bounds__(256)
void frangi_label_kernel(const float* __restrict__ img,
                         int* __restrict__ labels,
                         int* __restrict__ sizes,
                         KTab kt)
{
  __shared__ float sIn[SROWS*SSTR];    // 12000 B
  __shared__ float t0[32*TSTR];        // 8704 B x3
  __shared__ float t1[32*TSTR];
  __shared__ float t2[32*TSTR];

  const int tid    = threadIdx.x;
  const int imgIdx = blockIdx.y;
  const int tIdx   = blockIdx.x;
  const int tr0    = (tIdx >> 4) * 32;
  const int tc0    = (tIdx & 15) * 32;
  const float* __restrict__ im = img + (size_t)imgIdx * NPIX;

  // fill sIn: zeros outside, reflect('symmetric') + negate/scale inside.
  for (int idx = tid; idx < SROWS*64; idx += 256) {
    int r  = idx >> 6;
    int cs = idx & 63;
    if (cs < SSTR) {
      float v = 0.0f;
      if (cs >= 3 && cs < 53) {
        int gr = tr0 + r - 9;
        int gc = tc0 + cs - 12;
        gr = (gr < 0) ? (-1 - gr) : ((gr >= IMG_H) ? (2*IMG_H - 1 - gr) : gr);
        gc = (gc < 0) ? (-1 - gc) : ((gc >= IMG_W) ? (2*IMG_W - 1 - gc) : gc);
        v = -(im[gr*IMG_W + gc] * 500.0f);
      }
      sIn[r*SSTR + cs] = v;
    }
  }
  __syncthreads();

  float fr[4] = {0.0f, 0.0f, 0.0f, 0.0f};
  //        SIG RAD MLO GH L4P
  do_sigma<0,  4,  2,  6, 16>(sIn, t0, t1, t2, kt, tid, fr);  // sigma 1.0
  do_sigma<1,  5,  1,  6, 16>(sIn, t0, t1, t2, kt, tid, fr);  // sigma 1.3
  do_sigma<2,  6,  1,  6, 16>(sIn, t0, t1, t2, kt, tid, fr);  // sigma 1.6
  do_sigma<3,  8,  1,  7, 24>(sIn, t0, t1, t2, kt, tid, fr);  // sigma 1.9
  do_sigma<4,  9,  0,  7, 24>(sIn, t0, t1, t2, kt, tid, fr);  // sigma 2.2

  const int r  = tid >> 3;
  const int c0 = (tid & 7) * 4;
  const int gr = tr0 + r;
  const size_t imgBase = (size_t)imgIdx * NPIX;
#pragma unroll
  for (int k = 0; k < 4; ++k) {
    int p = gr*IMG_W + tc0 + c0 + k;
    float x = im[p];
    bool m = (x >= 0.1f) && (x <= 0.5f) && (fr[k] >= 0.2f);
    labels[imgBase + p] = m ? p : -1;
    sizes[imgBase + p]  = 0;
  }
}

// ---------------------------------------------------------------------------
// 8-connected CCL: atomic union-find (min-index root), then size filter.
// merge/output vectorized 4 px/thread; label sign is invariant during merge,
// so snapshot int4 mask checks are safe.
// ---------------------------------------------------------------------------
__device__ __forceinline__ int ldA(const int* p) {
  return __hip_atomic_load(p, __ATOMIC_RELAXED, __HIP_MEMORY_SCOPE_AGENT);
}
__device__ __forceinline__ int rootOf(const int* L, int x) {
  int pa = ldA(&L[x]);
  while (pa != x) { int g = ldA(&L[pa]); x = pa; pa = g; }
  return x;
}
__device__ __forceinline__ void unite(int* L, int a, int b) {
  while (true) {
    a = rootOf(L, a);
    b = rootOf(L, b);
    if (a == b) return;
    int hi = a > b ? a : b;
    int lo = a ^ b ^ hi;
    int old = atomicCAS(&L[hi], hi, lo);       // link high root under low root
    if (old == hi) return;
    a = old; b = lo;
  }
}

__global__ __launch_bounds__(256)
void merge_kernel(int* __restrict__ labels)
{
  int qid = blockIdx.x*256 + threadIdx.x;      // quad id (4 px, row-aligned)
  int img = qid >> 16;
  int q   = qid & 65535;
  int* L  = labels + ((size_t)img << 18);
  int p0  = q << 2;
  const int4 l4 = *(const int4*)(L + p0);
  if ((l4.x & l4.y & l4.z & l4.w) < 0) return; // all background
  int la[4] = {l4.x, l4.y, l4.z, l4.w};
  int r = p0 >> 9, c = p0 & 511;
  // W edges
  if (la[0] >= 0 && c > 0 && ldA(&L[p0-1]) >= 0) unite(L, p0, p0-1);
#pragma unroll
  for (int k = 1; k < 4; ++k)
    if (la[k] >= 0 && la[k-1] >= 0) unite(L, p0+k, p0+k-1);
  // N / NW / NE edges
  if (r > 0) {
    const int4 u4 = *(const int4*)(L + p0 - 512);
    int ua[4] = {u4.x, u4.y, u4.z, u4.w};
#pragma unroll
    for (int k = 0; k < 4; ++k) {
      if (la[k] < 0) continue;
      int p = p0 + k;
      if (ua[k] >= 0) unite(L, p, p - 512);
      if (k > 0) { if (ua[k-1] >= 0) unite(L, p, p - 513); }
      else if (c > 0 && ldA(&L[p0-513]) >= 0) unite(L, p0, p0-513);
      if (k < 3) { if (ua[k+1] >= 0) unite(L, p, p - 511); }
      else if (c < 508 && ldA(&L[p0-508]) >= 0) unite(L, p0+3, p0-508);
    }
  }
}

// compress to root + run-length-aggregated size count, fused (1 px/thread:
// wave-RLE keeps atomic count low on giant components).
__global__ __launch_bounds__(256)
void compress_count_kernel(int* __restrict__ labels, int* __restrict__ sizes)
{
  int gid = blockIdx.x*256 + threadIdx.x;
  int img = gid >> 18;
  int p   = gid & (NPIX - 1);
  int* L  = labels + ((size_t)img << 18);
  int rt  = -1;
  if (ldA(&L[p]) >= 0) {
    rt = rootOf(L, p);
    __hip_atomic_store(&L[p], rt, __ATOMIC_RELAXED, __HIP_MEMORY_SCOPE_AGENT);
  }
  int lane = threadIdx.x & 63;
  int left = __shfl_up(rt, 1);
  bool head = (lane == 0) || (left != rt);
  unsigned long long hb = __ballot(head);
  if (rt >= 0 && head) {
    unsigned long long rest = (hb >> 1) >> lane;   // heads strictly above
    int len = rest ? __ffsll((long long)rest) : (64 - lane);
    atomicAdd(&sizes[((size_t)img << 18) + rt], len);
  }
}

__global__ __launch_bounds__(256)
void output_kernel(const int* __restrict__ labels, const int* __restrict__ sizes,
                   float* __restrict__ out)
{
  int qid = blockIdx.x*256 + threadIdx.x;
  int img = qid >> 16;
  const int4 l4 = *(const int4*)(labels + ((size_t)qid << 2));
  const int* S = sizes + ((size_t)img << 18);
  float4 o;
  o.x = (l4.x >= 0 && S[l4.x] >= MIN_SZ) ? 1.0f : 0.0f;
  o.y = (l4.y >= 0 && S[l4.y] >= MIN_SZ) ? 1.0f : 0.0f;
  o.z = (l4.z >= 0 && S[l4.z] >= MIN_SZ) ? 1.0f : 0.0f;
  o.w = (l4.w >= 0 && S[l4.w] >= MIN_SZ) ? 1.0f : 0.0f;
  *(float4*)(out + ((size_t)qid << 2)) = o;
}

// ---------------------------------------------------------------------------
// Host: scipy.ndimage-style Gaussian derivative kernels (truncate=4), double
// precision exactly as numpy computes them, cast to f32.
// ---------------------------------------------------------------------------
static void gauss1d(double sigma, int order, int rad, float* out)
{
  int L = 2*rad + 1;
  double phi[24];
  double s = 0.0;
  for (int i = 0; i < L; ++i) {
    double x = (double)(i - rad);
    phi[i] = exp(-0.5*x*x/(sigma*sigma));
    s += phi[i];
  }
  for (int i = 0; i < L; ++i) phi[i] /= s;
  if (order == 0) {
    for (int i = 0; i < L; ++i) out[i] = (float)phi[i];
    return;
  }
  double q[3] = {1.0, 0.0, 0.0};
  for (int it = 0; it < order; ++it) {
    double nq[3] = {0.0, 0.0, 0.0};
    for (int i = 0; i <= order; ++i) {
      double v = 0.0;
      if (i+1 <= order) v += (double)(i+1) * q[i+1];
      if (i-1 >= 0)     v += (-1.0/(sigma*sigma)) * q[i-1];
      nq[i] = v;
    }
    q[0] = nq[0]; q[1] = nq[1]; q[2] = nq[2];
  }
  for (int i = 0; i < L; ++i) {
    double x = (double)(i - rad);
    double poly = q[0];
    double xp = x;
    for (int e = 1; e <= order; ++e) { poly += xp*q[e]; xp *= x; }
    out[i] = (float)(poly*phi[i]);
  }
}

extern "C" void kernel_launch(void* const* d_in, const int* in_sizes, int n_in,
                              void* d_out, int out_size, void* d_ws, size_t ws_size,
                              hipStream_t stream)
{
  (void)in_sizes; (void)n_in; (void)out_size; (void)ws_size;
  const float* img = (const float*)d_in[0];
  float* out = (float*)d_out;
  int* labels = (int*)d_ws;
  int* sizes  = labels + (size_t)NIMG * NPIX;

  KTab kt;
  memset(&kt, 0, sizeof(kt));
  for (int s = 0; s < NSIG; ++s) {
    double sigma = 1.0 + 0.3 * (double)s;      // np.arange(1.0, 2.5, 0.3)
    int rad = (int)(4.0 * sigma + 0.5);        // 4,5,6,8,9
    int L   = 2*rad + 1;
    int dlt = (12 - rad) & 3;                  // horizontal alignment shift
    kt.s2[s] = (float)(sigma * sigma);
    float k[3][24];
    for (int o = 0; o < 3; ++o) gauss1d(sigma, o, rad, k[o]);
    for (int o = 0; o < 3; ++o) {
      for (int j = 0; j < L; ++j)
        kt.kv[s][o][j] = k[o][L-1-j];          // pre-reversed (conv order)
      for (int jp = 0; jp < KHL; ++jp)
        kt.kh[s][o][jp] = (jp >= dlt && jp - dlt < L) ? k[o][L-1-(jp-dlt)] : 0.0f;
    }
  }

  dim3 gridF(NPIX / (32*32), NIMG);            // 256 tiles x 16 images
  frangi_label_kernel<<<gridF, 256, 0, stream>>>(img, labels, sizes, kt);

  int qblocks = (NIMG * NPIX / 4) / 256;       // 4096
  int pblocks = (NIMG * NPIX) / 256;           // 16384
  merge_kernel         <<<qblocks, 256, 0, stream>>>(labels);
  compress_count_kernel<<<pblocks, 256, 0, stream>>>(labels, sizes);
  output_kernel        <<<qblocks, 256, 0, stream>>>(labels, sizes, out);
}